// Round 3
// baseline (335.623 us; speedup 1.0000x reference)
//
#include <hip/hip_runtime.h>

// Problem constants
#define B_ 32
#define N_ 4096
#define C_ 768
#define H_ 8
#define DH_ 96
#define TILE 8
#define ROWS 256
#define NTILES (ROWS / TILE)   // 32
#define NCH (N_ / ROWS)        // 16 chunks per batch row

struct F3 { float x, y, z; };

// raw barrier: LDS-drain + barrier, no vmcnt drain (keeps global loads in flight)
#define BAR() do { asm volatile("s_waitcnt lgkmcnt(0)" ::: "memory"); \
                   __builtin_amdgcn_s_barrier();                      \
                   asm volatile("" ::: "memory"); } while (0)

// ---- q[e] = sum_c queries[c] * Wq[e,c] ------------------------------------
__global__ void k_q(const float* __restrict__ queries, const float* __restrict__ Wq,
                    float* __restrict__ q) {
  int e = blockIdx.x;
  int lane = threadIdx.x;
  const float* row = Wq + (size_t)e * C_;
  float acc = 0.f;
#pragma unroll
  for (int p = 0; p < 3; ++p) {
    int c = p * 256 + lane * 4;
    float4 w = *(const float4*)(row + c);
    float4 qa = *(const float4*)(queries + c);
    acc += w.x * qa.x + w.y * qa.y + w.z * qa.z + w.w * qa.w;
  }
#pragma unroll
  for (int off = 32; off; off >>= 1) acc += __shfl_xor(acc, off);
  if (lane == 0) q[e] = acc;
}

// ---- wq_eff[h,c] = sum_d q[h*DH+d] * Wkv[h*DH+d, c] -----------------------
__global__ void k_wqeff(const float* __restrict__ q, const float* __restrict__ Wkv,
                        float* __restrict__ wqe) {
  int i = blockIdx.x * 256 + threadIdx.x;
  int h = i / C_;
  int c = i - h * C_;
  const float* qh = q + h * DH_;
  float acc = 0.f;
  for (int d = 0; d < DH_; ++d)
    acc = fmaf(qh[d], Wkv[(size_t)(h * DH_ + d) * C_ + c], acc);
  wqe[i] = acc;
}

// ---- single-pass fused: online softmax + weighted accumulation ------------
// grid (NCH, B_), block 256 (4 waves). x read from HBM exactly once.
__global__ __launch_bounds__(256, 2) void k_fused(
    const float* __restrict__ x, const float* __restrict__ wqe,
    float* __restrict__ part, float* __restrict__ mout, float* __restrict__ sout) {
  __shared__ float xbuf[2][TILE * C_];   // 48 KB double-buffered x tile
  __shared__ float sdp[TILE][4][8];      // dot partials [row][lane-group][head]
  __shared__ float sw[H_][TILE];         // per-tile exp weights
  __shared__ float sscale[H_];           // per-tile rescale factor
  __shared__ float sm[H_];               // running max
  __shared__ float ss[H_];               // running sum

  const int ch = blockIdx.x, b = blockIdx.y;
  const int tid = threadIdx.x, lane = tid & 63, wid = tid >> 6;
  const float* xc = x + ((size_t)b * N_ + (size_t)ch * ROWS) * C_;

  if (tid < H_) { sm[tid] = -1e30f; ss[tid] = 0.f; }

  // wqe in registers: lane owns cols {p*256 + lane*4 .. +4}
  float4 wq[3][H_];
#pragma unroll
  for (int p = 0; p < 3; ++p)
#pragma unroll
    for (int h = 0; h < H_; ++h)
      wq[p][h] = *(const float4*)(wqe + h * C_ + p * 256 + lane * 4);

  // output accumulator: thread owns cols {tid*3 .. tid*3+2} for all 8 heads
  float acc[H_][3];
#pragma unroll
  for (int h = 0; h < H_; ++h) { acc[h][0] = 0.f; acc[h][1] = 0.f; acc[h][2] = 0.f; }

  // staging registers (24 VGPR): one 24 KB tile = 6 rounds of 4 KB
  float4 st[6];
  // prologue: tile 0 -> LDS buf0; tile 1 -> regs
#pragma unroll
  for (int j = 0; j < 6; ++j) st[j] = *(const float4*)(xc + j * 1024 + tid * 4);
#pragma unroll
  for (int j = 0; j < 6; ++j) *(float4*)(&xbuf[0][j * 1024 + tid * 4]) = st[j];
#pragma unroll
  for (int j = 0; j < 6; ++j) st[j] = *(const float4*)(xc + TILE * C_ + j * 1024 + tid * 4);
  BAR();

  for (int t = 0; t < NTILES; ++t) {
    const int cur = t & 1;
    const float* xb = xbuf[cur];
    // write tile t+1 (in regs) to the other buffer; issue loads for tile t+2
    if (t + 1 < NTILES) {
      float* bn = xbuf[cur ^ 1];
#pragma unroll
      for (int j = 0; j < 6; ++j) *(float4*)(&bn[j * 1024 + tid * 4]) = st[j];
    }
    if (t + 2 < NTILES) {
      const float* gt = xc + (size_t)(t + 2) * TILE * C_;
#pragma unroll
      for (int j = 0; j < 6; ++j) st[j] = *(const float4*)(gt + j * 1024 + tid * 4);
    }

    // ---- Phase A: dots for 8 rows x 8 heads (wave wid: rows 2wid,2wid+1) --
#pragma unroll
    for (int rr = 0; rr < 2; ++rr) {
      int r = wid * 2 + rr;
      const float* xr = xb + r * C_;
      float4 xv[3];
#pragma unroll
      for (int p = 0; p < 3; ++p) xv[p] = *(const float4*)(xr + p * 256 + lane * 4);
      float a[H_];
#pragma unroll
      for (int h = 0; h < H_; ++h) a[h] = 0.f;
#pragma unroll
      for (int p = 0; p < 3; ++p)
#pragma unroll
        for (int h = 0; h < H_; ++h) {
          a[h] = fmaf(xv[p].x, wq[p][h].x, a[h]);
          a[h] = fmaf(xv[p].y, wq[p][h].y, a[h]);
          a[h] = fmaf(xv[p].z, wq[p][h].z, a[h]);
          a[h] = fmaf(xv[p].w, wq[p][h].w, a[h]);
        }
#pragma unroll
      for (int h = 0; h < H_; ++h)
#pragma unroll
        for (int off = 1; off <= 8; off <<= 1)
          a[h] += __shfl_xor(a[h], off);
      if ((lane & 15) == 0) {
        int g = lane >> 4;
        *(float4*)(&sdp[r][g][0]) = make_float4(a[0], a[1], a[2], a[3]);
        *(float4*)(&sdp[r][g][4]) = make_float4(a[4], a[5], a[6], a[7]);
      }
    }
    BAR();

    // ---- Phase B: online softmax update (wave wid: heads 2wid,2wid+1) -----
    {
      int r = lane & 7;   // all lanes compute; groups replicate
#pragma unroll
      for (int hh = 0; hh < 2; ++hh) {
        int h = wid * 2 + hh;
        float d = sdp[r][0][h] + sdp[r][1][h] + sdp[r][2][h] + sdp[r][3][h];
        float tm = d;
#pragma unroll
        for (int off = 1; off <= 4; off <<= 1) tm = fmaxf(tm, __shfl_xor(tm, off));
        float mo = sm[h];
        float mn = fmaxf(mo, tm);
        float w = __expf(d - mn);
        float sum = w;
#pragma unroll
        for (int off = 1; off <= 4; off <<= 1) sum += __shfl_xor(sum, off);
        if (lane < 8) sw[h][lane] = w;
        if (lane == 0) {
          float sc = __expf(mo - mn);
          sscale[h] = sc;
          sm[h] = mn;
          ss[h] = ss[h] * sc + sum;
        }
      }
    }
    BAR();

    // ---- Phase C: acc[h][c-slice] = acc*scale + sum_r w[h][r]*x[r][c] -----
    {
      float4 sc0 = *(const float4*)&sscale[0];
      float4 sc1 = *(const float4*)&sscale[4];
      if (sc0.x != 1.f || sc0.y != 1.f || sc0.z != 1.f || sc0.w != 1.f ||
          sc1.x != 1.f || sc1.y != 1.f || sc1.z != 1.f || sc1.w != 1.f) {
        float s8[8] = {sc0.x, sc0.y, sc0.z, sc0.w, sc1.x, sc1.y, sc1.z, sc1.w};
#pragma unroll
        for (int h = 0; h < H_; ++h) {
          acc[h][0] *= s8[h]; acc[h][1] *= s8[h]; acc[h][2] *= s8[h];
        }
      }
      const int c0 = tid * 3;
#pragma unroll
      for (int r4 = 0; r4 < TILE; r4 += 4) {
        float4 wv[H_];
#pragma unroll
        for (int h = 0; h < H_; ++h) wv[h] = *(const float4*)&sw[h][r4];
#pragma unroll
        for (int k = 0; k < 4; ++k) {
          F3 xv = *(const F3*)(xb + (r4 + k) * C_ + c0);
#pragma unroll
          for (int h = 0; h < H_; ++h) {
            float wk = (k == 0) ? wv[h].x : (k == 1) ? wv[h].y
                     : (k == 2) ? wv[h].z : wv[h].w;
            acc[h][0] = fmaf(wk, xv.x, acc[h][0]);
            acc[h][1] = fmaf(wk, xv.y, acc[h][1]);
            acc[h][2] = fmaf(wk, xv.z, acc[h][2]);
          }
        }
      }
    }
    BAR();
  }

  // ---- epilogue: write chunk partials + (m,s) -------------------------------
  {
    const int c0 = tid * 3;
    float* pp = part + ((size_t)(ch * B_ + b) * H_) * C_ + c0;
#pragma unroll
    for (int h = 0; h < H_; ++h) {
      F3 o = { acc[h][0], acc[h][1], acc[h][2] };
      *(F3*)(pp + (size_t)h * C_) = o;
    }
    if (tid < H_) {
      mout[((size_t)b * H_ + tid) * NCH + ch] = sm[tid];
      sout[((size_t)b * H_ + tid) * NCH + ch] = ss[tid];
    }
  }
}

// ---- combine chunk partials with LSE merge -> xbar ------------------------
__global__ __launch_bounds__(256) void k_comb2(const float* __restrict__ part,
    const float* __restrict__ mpart, const float* __restrict__ spart,
    float* __restrict__ xbar) {
  int i = blockIdx.x * 256 + threadIdx.x;     // < B*H*C
  int bh = i / C_;
  const float* m = mpart + (size_t)bh * NCH;
  const float* s = spart + (size_t)bh * NCH;
  float M = -1e30f;
#pragma unroll
  for (int ch = 0; ch < NCH; ++ch) M = fmaxf(M, m[ch]);
  float denom = 0.f, acc = 0.f;
#pragma unroll 4
  for (int ch = 0; ch < NCH; ++ch) {
    float w = __expf(m[ch] - M);
    denom += w * s[ch];
    acc = fmaf(w, part[(size_t)ch * (B_ * H_ * C_) + i], acc);
  }
  xbar[i] = acc / denom;
}

// ---- out1[b,e] = sum_c xbar[b, e/DH, c] * Wkv[C+e, c] ---------------------
__global__ __launch_bounds__(256) void k_out1(const float* __restrict__ xbar,
    const float* __restrict__ Wkv, float* __restrict__ out1) {
  int b = blockIdx.y;
  int wv = threadIdx.x >> 6, lane = threadIdx.x & 63;
  int e0 = blockIdx.x * 64 + wv * 16;
  for (int it = 0; it < 16; ++it) {
    int e = e0 + it;
    int h = e / DH_;
    const float* wr = Wkv + (size_t)(C_ + e) * C_;
    const float* xr = xbar + ((size_t)b * H_ + h) * C_;
    float acc = 0.f;
#pragma unroll
    for (int p = 0; p < 3; ++p) {
      int c = p * 256 + lane * 4;
      float4 w = *(const float4*)(wr + c);
      float4 xv = *(const float4*)(xr + c);
      acc += w.x * xv.x + w.y * xv.y + w.z * xv.z + w.w * xv.w;
    }
#pragma unroll
    for (int off = 32; off; off >>= 1) acc += __shfl_xor(acc, off);
    if (lane == 0) out1[(size_t)b * C_ + e] = acc;
  }
}

// ---- y[b,e] = sum_c out1[b,c] * Wproj[e,c] + bproj[e] ---------------------
__global__ __launch_bounds__(256) void k_proj(const float* __restrict__ out1,
    const float* __restrict__ Wproj, const float* __restrict__ bproj,
    float* __restrict__ y) {
  int b = blockIdx.y;
  int wv = threadIdx.x >> 6, lane = threadIdx.x & 63;
  int e0 = blockIdx.x * 64 + wv * 16;
  const float* xr = out1 + (size_t)b * C_;
  for (int it = 0; it < 16; ++it) {
    int e = e0 + it;
    const float* wr = Wproj + (size_t)e * C_;
    float acc = 0.f;
#pragma unroll
    for (int p = 0; p < 3; ++p) {
      int c = p * 256 + lane * 4;
      float4 w = *(const float4*)(wr + c);
      float4 xv = *(const float4*)(xr + c);
      acc += w.x * xv.x + w.y * xv.y + w.z * xv.z + w.w * xv.w;
    }
#pragma unroll
    for (int off = 32; off; off >>= 1) acc += __shfl_xor(acc, off);
    if (lane == 0) y[(size_t)b * C_ + e] = acc + bproj[e];
  }
}

extern "C" void kernel_launch(void* const* d_in, const int* in_sizes, int n_in,
                              void* d_out, int out_size, void* d_ws, size_t ws_size,
                              hipStream_t stream) {
  const float* x       = (const float*)d_in[0];
  const float* queries = (const float*)d_in[1];
  const float* Wq      = (const float*)d_in[2];
  const float* Wkv     = (const float*)d_in[3];
  const float* Wproj   = (const float*)d_in[4];
  const float* bproj   = (const float*)d_in[5];
  float* y  = (float*)d_out;
  float* ws = (float*)d_ws;

  float* q     = ws;                                  // 768
  float* wqe   = ws + 1024;                           // 6144
  float* mpart = ws + 8192;                           // B*H*NCH = 4096
  float* spart = ws + 12288;                          // 4096
  float* part  = ws + 16384;                          // NCH*B*H*C = 3145728
  float* xbar  = part + (size_t)NCH * B_ * H_ * C_;   // 196608
  float* out1  = xbar + (size_t)B_ * H_ * C_;         // 24576

  hipLaunchKernelGGL(k_q,     dim3(C_),            dim3(64),  0, stream, queries, Wq, q);
  hipLaunchKernelGGL(k_wqeff, dim3(H_ * C_ / 256), dim3(256), 0, stream, q, Wkv, wqe);
  hipLaunchKernelGGL(k_fused, dim3(NCH, B_),       dim3(256), 0, stream,
                     x, wqe, part, mpart, spart);
  hipLaunchKernelGGL(k_comb2, dim3(B_ * H_ * C_ / 256), dim3(256), 0, stream,
                     part, mpart, spart, xbar);
  hipLaunchKernelGGL(k_out1,  dim3(12, B_),        dim3(256), 0, stream, xbar, Wkv, out1);
  hipLaunchKernelGGL(k_proj,  dim3(12, B_),        dim3(256), 0, stream, out1, Wproj, bproj, y);
}

// Round 4
// 205.071 us; speedup vs baseline: 1.6366x; 1.6366x over previous
//
#include <hip/hip_runtime.h>

// Problem constants
#define B_ 32
#define N_ 4096
#define C_ 768
#define H_ 8
#define DH_ 96
#define TILE 8
#define ROWS 256
#define NTILES (ROWS / TILE)   // 32
#define NCH (N_ / ROWS)        // 16

struct F3 { float x, y, z; };

// phase barrier: drain LDS ops, do NOT drain vmcnt (keeps staged loads in flight)
#define BARL() do { asm volatile("s_waitcnt lgkmcnt(0)" ::: "memory"); \
                    __builtin_amdgcn_s_barrier(); } while (0)

// ---- q[e] = sum_c queries[c] * Wq[e,c] ------------------------------------
__global__ void k_q(const float* __restrict__ queries, const float* __restrict__ Wq,
                    float* __restrict__ q) {
  int e = blockIdx.x;
  int lane = threadIdx.x;
  const float* row = Wq + (size_t)e * C_;
  float acc = 0.f;
#pragma unroll
  for (int p = 0; p < 3; ++p) {
    int c = p * 256 + lane * 4;
    float4 w = *(const float4*)(row + c);
    float4 qa = *(const float4*)(queries + c);
    acc += w.x * qa.x + w.y * qa.y + w.z * qa.z + w.w * qa.w;
  }
#pragma unroll
  for (int off = 32; off; off >>= 1) acc += __shfl_xor(acc, off);
  if (lane == 0) q[e] = acc;
}

// ---- wq_eff[h,c] = sum_d q[h*DH+d] * Wkv[h*DH+d, c] -----------------------
__global__ void k_wqeff(const float* __restrict__ q, const float* __restrict__ Wkv,
                        float* __restrict__ wqe) {
  int i = blockIdx.x * 256 + threadIdx.x;
  int h = i / C_;
  int c = i - h * C_;
  const float* qh = q + h * DH_;
  float acc = 0.f;
  for (int d = 0; d < DH_; ++d)
    acc = fmaf(qh[d], Wkv[(size_t)(h * DH_ + d) * C_ + c], acc);
  wqe[i] = acc;
}

// ---- single-pass fused: online softmax + weighted accumulation ------------
// grid (NCH, B_) = 512 blocks, 256 threads (4 waves). x read from HBM once,
// staged direct-to-LDS via global_load_lds, consumed twice from LDS.
__global__ __launch_bounds__(256) void k_fused(
    const float* __restrict__ x, const float* __restrict__ wqe,
    float* __restrict__ part, float* __restrict__ mout, float* __restrict__ sout) {
  __shared__ float xbuf[2][TILE * C_];   // 48 KB double-buffered x tile
  __shared__ float sdp[TILE][4][9];      // dot partials, padded stride 9
  __shared__ float sw[H_][TILE];         // per-tile exp weights
  __shared__ float sscale[H_];           // per-tile rescale factor
  __shared__ float sm[H_];               // running max (owned per wave pair)
  __shared__ float ss[H_];               // running sum

  const int ch = blockIdx.x, b = blockIdx.y;
  const int tid = threadIdx.x, lane = tid & 63, wid = tid >> 6;
  const int h0 = wid * 2, h1 = h0 + 1;
  const float* xc = x + ((size_t)b * N_ + (size_t)ch * ROWS) * C_;

  if (tid < H_) { sm[tid] = -1e30f; ss[tid] = 0.f; }

  // wq for this wave's two heads: 24 VGPR
  float4 wq[3][2];
#pragma unroll
  for (int p = 0; p < 3; ++p) {
    wq[p][0] = *(const float4*)(wqe + h0 * C_ + p * 256 + lane * 4);
    wq[p][1] = *(const float4*)(wqe + h1 * C_ + p * 256 + lane * 4);
  }

  // output accumulator: thread owns cols {tid*3..+2} for all 8 heads (24 VGPR)
  float acc[H_][3];
#pragma unroll
  for (int h = 0; h < H_; ++h) { acc[h][0] = 0.f; acc[h][1] = 0.f; acc[h][2] = 0.f; }

#define STAGE(BUF, T) do {                                                     \
    const float* gt_ = xc + (size_t)(T) * TILE * C_;                           \
    float* bn_ = xbuf[BUF];                                                    \
    _Pragma("unroll")                                                          \
    for (int j = 0; j < 6; ++j) {                                              \
      int k = wid * 6 + j;                                                     \
      __builtin_amdgcn_global_load_lds(                                        \
        (const __attribute__((address_space(1))) void*)(gt_ + k * 256 + lane * 4), \
        (__attribute__((address_space(3))) void*)(bn_ + k * 256),              \
        16, 0, 0);                                                             \
    }                                                                          \
  } while (0)

  // prologue: tile 0 -> buf0, wait, barrier (also publishes sm/ss init)
  STAGE(0, 0);
  asm volatile("s_waitcnt vmcnt(0) lgkmcnt(0)" ::: "memory");
  __builtin_amdgcn_s_barrier();

  for (int t = 0; t < NTILES; ++t) {
    const int cur = t & 1;
    const float* xb = xbuf[cur];
    if (t + 1 < NTILES) STAGE(cur ^ 1, t + 1);   // hides under phases A-C

    // ---- Phase A: dots for 8 rows, this wave's 2 heads --------------------
#pragma unroll
    for (int r = 0; r < TILE; ++r) {
      const float* xr = xb + r * C_;
      float4 xv0 = *(const float4*)(xr + 0 * 256 + lane * 4);
      float4 xv1 = *(const float4*)(xr + 1 * 256 + lane * 4);
      float4 xv2 = *(const float4*)(xr + 2 * 256 + lane * 4);
      float a0, a1;
      a0  = xv0.x * wq[0][0].x; a1  = xv0.x * wq[0][1].x;
      a0 = fmaf(xv0.y, wq[0][0].y, a0); a1 = fmaf(xv0.y, wq[0][1].y, a1);
      a0 = fmaf(xv0.z, wq[0][0].z, a0); a1 = fmaf(xv0.z, wq[0][1].z, a1);
      a0 = fmaf(xv0.w, wq[0][0].w, a0); a1 = fmaf(xv0.w, wq[0][1].w, a1);
      a0 = fmaf(xv1.x, wq[1][0].x, a0); a1 = fmaf(xv1.x, wq[1][1].x, a1);
      a0 = fmaf(xv1.y, wq[1][0].y, a0); a1 = fmaf(xv1.y, wq[1][1].y, a1);
      a0 = fmaf(xv1.z, wq[1][0].z, a0); a1 = fmaf(xv1.z, wq[1][1].z, a1);
      a0 = fmaf(xv1.w, wq[1][0].w, a0); a1 = fmaf(xv1.w, wq[1][1].w, a1);
      a0 = fmaf(xv2.x, wq[2][0].x, a0); a1 = fmaf(xv2.x, wq[2][1].x, a1);
      a0 = fmaf(xv2.y, wq[2][0].y, a0); a1 = fmaf(xv2.y, wq[2][1].y, a1);
      a0 = fmaf(xv2.z, wq[2][0].z, a0); a1 = fmaf(xv2.z, wq[2][1].z, a1);
      a0 = fmaf(xv2.w, wq[2][0].w, a0); a1 = fmaf(xv2.w, wq[2][1].w, a1);
#pragma unroll
      for (int off = 1; off <= 8; off <<= 1) {
        a0 += __shfl_xor(a0, off);
        a1 += __shfl_xor(a1, off);
      }
      if ((lane & 15) == 0) {
        int g = lane >> 4;
        sdp[r][g][h0] = a0;
        sdp[r][g][h1] = a1;
      }
    }
    BARL();

    // ---- Phase B: online softmax update for this wave's 2 heads -----------
    {
      int r = lane & 7;   // 8 replicated groups compute identically
      float d0 = (sdp[r][0][h0] + sdp[r][1][h0]) + (sdp[r][2][h0] + sdp[r][3][h0]);
      float d1 = (sdp[r][0][h1] + sdp[r][1][h1]) + (sdp[r][2][h1] + sdp[r][3][h1]);
      float tm0 = d0, tm1 = d1;
#pragma unroll
      for (int off = 1; off <= 4; off <<= 1) {
        tm0 = fmaxf(tm0, __shfl_xor(tm0, off));
        tm1 = fmaxf(tm1, __shfl_xor(tm1, off));
      }
      float mo0 = sm[h0], mo1 = sm[h1];
      float mn0 = fmaxf(mo0, tm0), mn1 = fmaxf(mo1, tm1);
      float w0 = __expf(d0 - mn0), w1 = __expf(d1 - mn1);
      float s0 = w0, s1 = w1;
#pragma unroll
      for (int off = 1; off <= 4; off <<= 1) {
        s0 += __shfl_xor(s0, off);
        s1 += __shfl_xor(s1, off);
      }
      if (lane < 8) { sw[h0][lane] = w0; sw[h1][lane] = w1; }
      if (lane == 0) {
        float sc0 = __expf(mo0 - mn0), sc1 = __expf(mo1 - mn1);
        sscale[h0] = sc0; sscale[h1] = sc1;
        sm[h0] = mn0; sm[h1] = mn1;
        ss[h0] = ss[h0] * sc0 + s0;
        ss[h1] = ss[h1] * sc1 + s1;
      }
    }
    BARL();

    // ---- Phase C: acc = acc*scale + sum_r w[h][r] * x[r][c-slice] ---------
    {
      float4 sc0 = *(const float4*)&sscale[0];
      float4 sc1 = *(const float4*)&sscale[4];
      if (sc0.x != 1.f || sc0.y != 1.f || sc0.z != 1.f || sc0.w != 1.f ||
          sc1.x != 1.f || sc1.y != 1.f || sc1.z != 1.f || sc1.w != 1.f) {
        float s8[8] = {sc0.x, sc0.y, sc0.z, sc0.w, sc1.x, sc1.y, sc1.z, sc1.w};
#pragma unroll
        for (int h = 0; h < H_; ++h) {
          acc[h][0] *= s8[h]; acc[h][1] *= s8[h]; acc[h][2] *= s8[h];
        }
      }
      const int c0 = tid * 3;
#pragma unroll
      for (int r4 = 0; r4 < TILE; r4 += 4) {
        float4 wv[H_];
#pragma unroll
        for (int h = 0; h < H_; ++h) wv[h] = *(const float4*)&sw[h][r4];
#pragma unroll
        for (int k = 0; k < 4; ++k) {
          F3 xv = *(const F3*)(xb + (r4 + k) * C_ + c0);
#pragma unroll
          for (int h = 0; h < H_; ++h) {
            float wk = (k == 0) ? wv[h].x : (k == 1) ? wv[h].y
                     : (k == 2) ? wv[h].z : wv[h].w;
            acc[h][0] = fmaf(wk, xv.x, acc[h][0]);
            acc[h][1] = fmaf(wk, xv.y, acc[h][1]);
            acc[h][2] = fmaf(wk, xv.z, acc[h][2]);
          }
        }
      }
    }
    // end of iter: tile t+1 must be resident before next phase A
    if (t + 1 < NTILES) { asm volatile("s_waitcnt vmcnt(0)" ::: "memory"); }
    BARL();
  }

  // ---- epilogue: write chunk partials + (m,s) -------------------------------
  {
    const int c0 = tid * 3;
    float* pp = part + ((size_t)(ch * B_ + b) * H_) * C_ + c0;
#pragma unroll
    for (int h = 0; h < H_; ++h) {
      F3 o = { acc[h][0], acc[h][1], acc[h][2] };
      *(F3*)(pp + (size_t)h * C_) = o;
    }
    if (tid < H_) {
      mout[((size_t)b * H_ + tid) * NCH + ch] = sm[tid];
      sout[((size_t)b * H_ + tid) * NCH + ch] = ss[tid];
    }
  }
#undef STAGE
}

// ---- combine chunk partials with LSE merge -> xbar ------------------------
__global__ __launch_bounds__(256) void k_comb2(const float* __restrict__ part,
    const float* __restrict__ mpart, const float* __restrict__ spart,
    float* __restrict__ xbar) {
  int i = blockIdx.x * 256 + threadIdx.x;     // < B*H*C
  int bh = i / C_;
  const float* m = mpart + (size_t)bh * NCH;
  const float* s = spart + (size_t)bh * NCH;
  float M = -1e30f;
#pragma unroll
  for (int ch = 0; ch < NCH; ++ch) M = fmaxf(M, m[ch]);
  float denom = 0.f, acc = 0.f;
#pragma unroll 4
  for (int ch = 0; ch < NCH; ++ch) {
    float w = __expf(m[ch] - M);
    denom += w * s[ch];
    acc = fmaf(w, part[(size_t)ch * (B_ * H_ * C_) + i], acc);
  }
  xbar[i] = acc / denom;
}

// ---- out1[b,e] = sum_c xbar[b, e/DH, c] * Wkv[C+e, c] ---------------------
__global__ __launch_bounds__(256) void k_out1(const float* __restrict__ xbar,
    const float* __restrict__ Wkv, float* __restrict__ out1) {
  int b = blockIdx.y;
  int wv = threadIdx.x >> 6, lane = threadIdx.x & 63;
  int e0 = blockIdx.x * 64 + wv * 16;
  for (int it = 0; it < 16; ++it) {
    int e = e0 + it;
    int h = e / DH_;
    const float* wr = Wkv + (size_t)(C_ + e) * C_;
    const float* xr = xbar + ((size_t)b * H_ + h) * C_;
    float acc = 0.f;
#pragma unroll
    for (int p = 0; p < 3; ++p) {
      int c = p * 256 + lane * 4;
      float4 w = *(const float4*)(wr + c);
      float4 xv = *(const float4*)(xr + c);
      acc += w.x * xv.x + w.y * xv.y + w.z * xv.z + w.w * xv.w;
    }
#pragma unroll
    for (int off = 32; off; off >>= 1) acc += __shfl_xor(acc, off);
    if (lane == 0) out1[(size_t)b * C_ + e] = acc;
  }
}

// ---- y[b,e] = sum_c out1[b,c] * Wproj[e,c] + bproj[e] ---------------------
__global__ __launch_bounds__(256) void k_proj(const float* __restrict__ out1,
    const float* __restrict__ Wproj, const float* __restrict__ bproj,
    float* __restrict__ y) {
  int b = blockIdx.y;
  int wv = threadIdx.x >> 6, lane = threadIdx.x & 63;
  int e0 = blockIdx.x * 64 + wv * 16;
  const float* xr = out1 + (size_t)b * C_;
  for (int it = 0; it < 16; ++it) {
    int e = e0 + it;
    const float* wr = Wproj + (size_t)e * C_;
    float acc = 0.f;
#pragma unroll
    for (int p = 0; p < 3; ++p) {
      int c = p * 256 + lane * 4;
      float4 w = *(const float4*)(wr + c);
      float4 xv = *(const float4*)(xr + c);
      acc += w.x * xv.x + w.y * xv.y + w.z * xv.z + w.w * xv.w;
    }
#pragma unroll
    for (int off = 32; off; off >>= 1) acc += __shfl_xor(acc, off);
    if (lane == 0) y[(size_t)b * C_ + e] = acc + bproj[e];
  }
}

extern "C" void kernel_launch(void* const* d_in, const int* in_sizes, int n_in,
                              void* d_out, int out_size, void* d_ws, size_t ws_size,
                              hipStream_t stream) {
  const float* x       = (const float*)d_in[0];
  const float* queries = (const float*)d_in[1];
  const float* Wq      = (const float*)d_in[2];
  const float* Wkv     = (const float*)d_in[3];
  const float* Wproj   = (const float*)d_in[4];
  const float* bproj   = (const float*)d_in[5];
  float* y  = (float*)d_out;
  float* ws = (float*)d_ws;

  float* q     = ws;                                  // 768
  float* wqe   = ws + 1024;                           // 6144
  float* mpart = ws + 8192;                           // B*H*NCH = 4096
  float* spart = ws + 12288;                          // 4096
  float* part  = ws + 16384;                          // NCH*B*H*C = 3145728
  float* xbar  = part + (size_t)NCH * B_ * H_ * C_;   // 196608
  float* out1  = xbar + (size_t)B_ * H_ * C_;         // 24576

  hipLaunchKernelGGL(k_q,     dim3(C_),            dim3(64),  0, stream, queries, Wq, q);
  hipLaunchKernelGGL(k_wqeff, dim3(H_ * C_ / 256), dim3(256), 0, stream, q, Wkv, wqe);
  hipLaunchKernelGGL(k_fused, dim3(NCH, B_),       dim3(256), 0, stream,
                     x, wqe, part, mpart, spart);
  hipLaunchKernelGGL(k_comb2, dim3(B_ * H_ * C_ / 256), dim3(256), 0, stream,
                     part, mpart, spart, xbar);
  hipLaunchKernelGGL(k_out1,  dim3(12, B_),        dim3(256), 0, stream, xbar, Wkv, out1);
  hipLaunchKernelGGL(k_proj,  dim3(12, B_),        dim3(256), 0, stream, out1, Wproj, bproj, y);
}